// Round 12
// baseline (959.144 us; speedup 1.0000x reference)
//
#include <hip/hip_runtime.h>
#include <hip/hip_fp16.h>
#include <cstdint>

// ---------------------------------------------------------------------------
// GCN Siamese. LDS-staged multisplit (dst>>8 buckets) -> per-bucket LDS
// counting sort -> node-major CSR -> fp8 gather aggregation with
// FEATURE-SPLIT half-tables (r12): XW8 stored as [2][N][32]; aggregation runs
// as two half-feature dispatches so each XCD's 4MB L2 fully holds the 3.2MB
// half-table. Wave = 1 node, 32 lanes/row, even/odd edge parity groups.
// N=100000, E=3.2M, G=1024
// ---------------------------------------------------------------------------

#define NBSH 8                      // 256 nodes per bucket
#define CAPB 10240                  // per-bucket capacity (mean 8184, ~23 sigma)
#define SPLIT_T 512
#define SPLIT_EPT 28
#define SPLIT_CHUNK (SPLIT_T * SPLIT_EPT)   // 14336

__device__ __forceinline__ float fatomic(float* p, float v) {
    return unsafeAtomicAdd(p, v);   // hw global_atomic_add_f32
}
__device__ __forceinline__ float bf2f(unsigned short u) {
    union { unsigned int i; float f; } c; c.i = ((unsigned int)u) << 16; return c.f;
}
__device__ __forceinline__ unsigned short f2bf(float f) {
    union { float f; unsigned int i; } c; c.f = f;
    const unsigned int b = c.i;
    return (unsigned short)((b + 0x7FFF + ((b >> 16) & 1)) >> 16);   // RNE
}

#if defined(__has_builtin)
#if __has_builtin(__builtin_amdgcn_cvt_f32_fp8) && __has_builtin(__builtin_amdgcn_cvt_pk_fp8_f32)
#define HW_FP8 1
#endif
#endif

// fp8 e4m3 decode
__device__ __forceinline__ float fp8dec(unsigned int b) {
#ifdef HW_FP8
    return __builtin_amdgcn_cvt_f32_fp8((int)b, 0);
#else
    const unsigned int mag = (b & 0x7Fu) << 20;
    const float f = __uint_as_float(mag) * __uint_as_float(0x7B800000u);
    const unsigned int r = __float_as_uint(f) | ((b & 0x80u) << 24);
    return __uint_as_float(r);
#endif
}

// f32 -> fp8 e4m3, RNE
__device__ __forceinline__ unsigned char fp8enc(float x) {
#ifdef HW_FP8
    const int v = __builtin_amdgcn_cvt_pk_fp8_f32(x, x, 0, false);
    return (unsigned char)(v & 0xFF);
#else
    const unsigned short h = __half_as_ushort(__float2half(x));
    const unsigned int s = (unsigned int)(h >> 15) << 7;
    const int e = (h >> 10) & 0x1F;
    const unsigned int m = h & 0x3FFu;
    if (e == 31) return (unsigned char)(s | 0x7E);
    if (e == 0) return (unsigned char)s;
    int E = e - 15 + 7;
    if (E >= 16) return (unsigned char)(s | 0x7E);
    if (E <= 0) {
        const unsigned int M = 0x400u | m;
        const int r = 16 - e;
        const unsigned int q = (M + (1u << (r - 1)) - 1u + ((M >> r) & 1u)) >> r;
        return (unsigned char)(s | (q > 7u ? 8u : q));
    }
    unsigned int q = (m + 63u + ((m >> 7) & 1u)) >> 7;
    if (q == 8u) { q = 0u; ++E; if (E >= 16) return (unsigned char)(s | 0x7E); }
    return (unsigned char)(s | ((unsigned int)E << 3) | q);
#endif
}

// ---- stage 1: multisplit into 391 buckets (dst>>8), dense run writes ------
__global__ __launch_bounds__(512) void k_split(const int* __restrict__ src,
                                               const int* __restrict__ dst,
                                               int* __restrict__ gcnt,
                                               int* __restrict__ colBkt,
                                               int E, int NBUK) {
    __shared__ int out[SPLIT_CHUNK];     // 57344 B
    __shared__ int bs[513];
    __shared__ int aux[512];
    const int t = threadIdx.x;
    const int e0 = blockIdx.x * SPLIT_CHUNK;

    int pk[SPLIT_EPT];
    int bk[SPLIT_EPT];

    aux[t] = 0;
    __syncthreads();

#pragma unroll
    for (int k = 0; k < SPLIT_EPT; ++k) {
        const int e = e0 + t + SPLIT_T * k;          // coalesced
        if (e < E) {
            const int d = dst[e];
            const int s = src[e];
            const int b = d >> NBSH;
            pk[k] = (s << NBSH) | (d & ((1 << NBSH) - 1));
            bk[k] = b;
            atomicAdd(&aux[b], 1);
        } else {
            bk[k] = -1;
        }
    }
    __syncthreads();

    for (int off = 1; off < 512; off <<= 1) {
        const int u = (t >= off) ? aux[t - off] : 0;
        __syncthreads();
        aux[t] += u;
        __syncthreads();
    }
    bs[t + 1] = aux[t];
    if (t == 0) bs[0] = 0;
    __syncthreads();

    aux[t] = 0;
    __syncthreads();

#pragma unroll
    for (int k = 0; k < SPLIT_EPT; ++k) {
        if (bk[k] >= 0) {
            const int pos = bs[bk[k]] + atomicAdd(&aux[bk[k]], 1);
            out[pos] = pk[k];
        }
    }
    __syncthreads();

    if (t < NBUK) {
        const int L = bs[t + 1] - bs[t];
        aux[t] = (L > 0) ? atomicAdd(&gcnt[t], L) : 0;   // goff
    } else if (t < 512) {
        aux[t] = 0;
    }
    __syncthreads();

    const int wid = t >> 6, lane = t & 63;
    for (int b = wid; b < NBUK; b += 8) {
        const int L = bs[b + 1] - bs[b];
        if (L == 0) continue;
        const int gp = aux[b];
        const size_t rb = (size_t)b * CAPB;
        for (int k = lane; k < L; k += 64) {
            const int p = gp + k;
            if (p < CAPB) colBkt[rb + p] = out[bs[b] + k];
        }
    }
}

// ---- stage 1b: scan bucket counts -> gbase ; rowstart[N] = total ----------
__global__ __launch_bounds__(512) void k_gscan(const int* __restrict__ gcnt,
                                               int* __restrict__ gbase,
                                               int* __restrict__ rowstart,
                                               int NBUK, int Nn) {
    __shared__ int sm[512];
    const int t = threadIdx.x;
    const int v = (t < NBUK) ? min(gcnt[t], CAPB) : 0;
    sm[t] = v;
    __syncthreads();
    for (int off = 1; off < 512; off <<= 1) {
        const int u = (t >= off) ? sm[t - off] : 0;
        __syncthreads();
        sm[t] += u;
        __syncthreads();
    }
    if (t < NBUK) gbase[t] = sm[t] - v;  // exclusive
    if (t == 511) rowstart[Nn] = sm[511];
}

// ---- stage 2: per-bucket LDS counting sort -> colN, rowstart, dinv --------
__global__ __launch_bounds__(256) void k_bsort(const int* __restrict__ colBkt,
                                               const int* __restrict__ gcnt,
                                               const int* __restrict__ gbase,
                                               int* __restrict__ colN,
                                               int* __restrict__ rowstart,
                                               float* __restrict__ dinv,
                                               int Nn) {
    __shared__ int in[CAPB];             // 40960 B
    __shared__ int lb[257];
    __shared__ int fill[256];
    const int b = blockIdx.x;
    const int t = threadIdx.x;
    const int L = min(gcnt[b], CAPB);
    const size_t rb = (size_t)b * CAPB;
    for (int k = t; k < L; k += 256) in[k] = colBkt[rb + k];
    fill[t] = 0;
    __syncthreads();
    for (int k = t; k < L; k += 256) atomicAdd(&fill[in[k] & 255], 1);
    __syncthreads();
    for (int off = 1; off < 256; off <<= 1) {
        const int u = (t >= off) ? fill[t - off] : 0;
        __syncthreads();
        fill[t] += u;
        __syncthreads();
    }
    lb[t + 1] = fill[t];
    if (t == 0) lb[0] = 0;
    __syncthreads();
    const int bb = gbase[b];
    const int node = (b << NBSH) + t;
    if (node < Nn) {
        rowstart[node] = bb + lb[t];
        dinv[node] = rsqrtf((float)(lb[t + 1] - lb[t]) + 1.0f);
    }
    fill[t] = 0;
    __syncthreads();
    for (int k = t; k < L; k += 256) {
        const int v = in[k];
        const int n = v & 255;
        const int pos = bb + lb[n] + atomicAdd(&fill[n], 1);
        colN[pos] = v >> NBSH;
    }
}

// Y[h][row][32] = fp8(dinv[row] * (X@W)[row]) for feature halves h=colf>>5
template <int K, bool BF16IN>
__global__ __launch_bounds__(256, 4) void k_mm(const void* __restrict__ Xv,
                                               const float* __restrict__ W,
                                               const float* __restrict__ dinv,
                                               unsigned char* __restrict__ Y, int n) {
    __shared__ float WL[K * 64];
    __shared__ float XT[32 * K];
    const int tid = threadIdx.x;
    for (int i = tid * 4; i < K * 64; i += 1024)
        *(float4*)&WL[i] = *(const float4*)&W[i];
    const int rowBase = blockIdx.x * 32;
    const int rows = min(32, n - rowBase);
    if (BF16IN) {
        const unsigned short* xs = (const unsigned short*)Xv + (size_t)rowBase * K;
        for (int i = tid * 4; i < rows * K; i += 1024) {
            const ushort4 u = *(const ushort4*)&xs[i];
            XT[i + 0] = bf2f(u.x); XT[i + 1] = bf2f(u.y);
            XT[i + 2] = bf2f(u.z); XT[i + 3] = bf2f(u.w);
        }
    } else {
        const float* xs = (const float*)Xv + (size_t)rowBase * K;
        for (int i = tid * 4; i < rows * K; i += 1024)
            *(float4*)&XT[i] = *(const float4*)&xs[i];
    }
    __syncthreads();
    const int colf = tid & 63;
    const int rg = tid >> 6;
    float acc[8] = {};
#pragma unroll 4
    for (int k4 = 0; k4 < K / 4; ++k4) {
        const float w0 = WL[(k4 * 4 + 0) * 64 + colf];
        const float w1 = WL[(k4 * 4 + 1) * 64 + colf];
        const float w2 = WL[(k4 * 4 + 2) * 64 + colf];
        const float w3 = WL[(k4 * 4 + 3) * 64 + colf];
#pragma unroll
        for (int r = 0; r < 8; ++r) {
            const float4 xv = *(const float4*)&XT[(rg * 8 + r) * K + k4 * 4];
            acc[r] += xv.x * w0 + xv.y * w1 + xv.z * w2 + xv.w * w3;
        }
    }
    const size_t hoff = (size_t)(colf >> 5) * n * 32 + (colf & 31);
#pragma unroll
    for (int r = 0; r < 8; ++r) {
        const int row = rowBase + rg * 8 + r;
        if (row < n) Y[hoff + (size_t)row * 32] = fp8enc(dinv[row] * acc[r]);
    }
}

// Half-feature CSR aggregation: wave = 1 node; lanes split into two 32-lane
// edge-parity groups, each gathering 32B fp8 half-rows; shfl_xor(32) merges.
// XWh points at half-table H; outputs go to feature slots [H*32, H*32+32).
template <bool POOL, int H>
__global__ __launch_bounds__(256) void k_aggh(const int* __restrict__ colN,
                                              const int* __restrict__ rowstart,
                                              const float* __restrict__ dinv,
                                              const unsigned char* __restrict__ XWh,
                                              const float* __restrict__ bias,
                                              unsigned short* __restrict__ Hout,
                                              const int* __restrict__ batch,
                                              float* __restrict__ emb,
                                              float* __restrict__ cnt, int Nn) {
    const int lane = threadIdx.x & 63;
    const int hg = lane >> 5;            // edge parity group (0: even j, 1: odd j)
    const int l32 = lane & 31;           // feature within half
    const int wid = (blockIdx.x * blockDim.x + threadIdx.x) >> 6;
    const int nw = (gridDim.x * blockDim.x) >> 6;
    const float bl = bias[H * 32 + l32];
    for (int i = wid; i < Nn; i += nw) {
        const int s = rowstart[i], e = rowstart[i + 1];
        float acc = 0.0f;
        int j = s + hg;
        for (; j + 14 < e; j += 16) {    // 8 edges per parity group per iter
            int c[8];
#pragma unroll
            for (int q = 0; q < 8; ++q) c[q] = colN[j + 2 * q];
            unsigned int b[8];
#pragma unroll
            for (int q = 0; q < 8; ++q) b[q] = XWh[(size_t)c[q] * 32 + l32];
            float t0 = 0.f, t1 = 0.f;
#pragma unroll
            for (int q = 0; q < 4; ++q) t0 += fp8dec(b[q]);
#pragma unroll
            for (int q = 4; q < 8; ++q) t1 += fp8dec(b[q]);
            acc += t0 + t1;
        }
        for (; j < e; j += 2)
            acc += fp8dec(XWh[(size_t)colN[j] * 32 + l32]);
        acc += __shfl_xor(acc, 32);      // merge even/odd parity partials
        const float di = dinv[i];
        const float self = fp8dec(XWh[(size_t)i * 32 + l32]);
        const float v = fmaxf(di * (acc + self) + bl, 0.0f);
        if (hg == 0) {
            if (POOL) {
                const int g = batch[i];
                fatomic(&emb[(size_t)g * 64 + H * 32 + l32], v);
                if (H == 0 && l32 == 0) fatomic(&cnt[g], 1.0f);
            } else {
                Hout[(size_t)i * 64 + H * 32 + l32] = f2bf(v);
            }
        }
    }
}

// head: emb -> [e1,e2,|e1-e2|] @ fc1 -> relu -> @ fc2 -> sigmoid
__global__ __launch_bounds__(64) void k_head(const float* __restrict__ emb1, const float* __restrict__ cnt1,
                                             const float* __restrict__ emb2, const float* __restrict__ cnt2,
                                             const float* __restrict__ fc1W, const float* __restrict__ fc1b,
                                             const float* __restrict__ fc2W, const float* __restrict__ fc2b,
                                             float* __restrict__ out) {
    const int g = blockIdx.x;
    const int lane = threadIdx.x;
    __shared__ float comb[192];
    const float c1 = fmaxf(cnt1[g], 1.0f), c2 = fmaxf(cnt2[g], 1.0f);
    const float e1 = emb1[g * 64 + lane] / c1;
    const float e2 = emb2[g * 64 + lane] / c2;
    comb[lane] = e1;
    comb[64 + lane] = e2;
    comb[128 + lane] = fabsf(e1 - e2);
    __syncthreads();
    float acc = fc1b[lane];
    for (int k = 0; k < 192; ++k) acc += comb[k] * fc1W[k * 64 + lane];
    const float o1 = fmaxf(acc, 0.0f);
    float p = o1 * fc2W[lane];
#pragma unroll
    for (int off = 32; off > 0; off >>= 1) p += __shfl_xor(p, off);
    if (lane == 0) out[g] = 1.0f / (1.0f + expf(-(p + fc2b[0])));
}

extern "C" void kernel_launch(void* const* d_in, const int* in_sizes, int n_in,
                              void* d_out, int out_size, void* d_ws, size_t ws_size,
                              hipStream_t stream) {
    const float* x1   = (const float*)d_in[0];
    const int*   ei1  = (const int*)d_in[1];
    const int*   bt1  = (const int*)d_in[2];
    const float* x2   = (const float*)d_in[3];
    const int*   ei2  = (const int*)d_in[4];
    const int*   bt2  = (const int*)d_in[5];
    const float* W1   = (const float*)d_in[6];
    const float* bb1  = (const float*)d_in[7];
    const float* W2   = (const float*)d_in[8];
    const float* bb2  = (const float*)d_in[9];
    const float* fc1W = (const float*)d_in[10];
    const float* fc1b = (const float*)d_in[11];
    const float* fc2W = (const float*)d_in[12];
    const float* fc2b = (const float*)d_in[13];
    float* out = (float*)d_out;

    const int N = in_sizes[0] / 128;
    const int E = in_sizes[1] / 2;
    const int G = out_size;
    const int NBUK = (N + 255) >> NBSH;              // 391
    const int nchunks = (E + SPLIT_CHUNK - 1) / SPLIT_CHUNK;

    // 16B-aligned workspace carve-out
    char* base = (char*)d_ws;
    size_t off = 0;
    auto carve = [&](size_t bytes) {
        void* p = base + off;
        off = (off + bytes + 15) & ~(size_t)15;
        return p;
    };
    float* dinv   = (float*)carve((size_t)N * 4);
    float* emb1   = (float*)carve((size_t)G * 64 * 4);
    float* cnt1   = (float*)carve((size_t)G * 4);
    float* emb2   = (float*)carve((size_t)G * 64 * 4);
    float* cnt2   = (float*)carve((size_t)G * 4);
    int* rowstart = (int*)carve((size_t)(N + 1) * 4);
    int* gcnt     = (int*)carve(512 * 4);
    int* gbase    = (int*)carve(512 * 4);
    int* colBkt   = (int*)carve((size_t)NBUK * CAPB * 4);   // 16.0 MB
    int* colN     = (int*)carve((size_t)E * 4);             // 12.8 MB
    unsigned char* XW8 = (unsigned char*)carve((size_t)N * 64);  // [2][N][32]
    unsigned short* H1 = (unsigned short*)colBkt;   // overlay (dead after bsort)

    const int mmGrid = (N + 31) / 32;

    for (int br = 0; br < 2; ++br) {
        const float* X = br ? x2 : x1;
        const int* ei  = br ? ei2 : ei1;
        const int* bt  = br ? bt2 : bt1;
        float* emb = br ? emb2 : emb1;
        float* cnt = br ? cnt2 : cnt1;
        const int* srcp = ei;
        const int* dstp = ei + E;

        hipMemsetAsync(gcnt, 0, 512 * 4, stream);
        k_split<<<nchunks, SPLIT_T, 0, stream>>>(srcp, dstp, gcnt, colBkt, E, NBUK);
        k_gscan<<<1, 512, 0, stream>>>(gcnt, gbase, rowstart, NBUK, N);
        k_bsort<<<NBUK, 256, 0, stream>>>(colBkt, gcnt, gbase, colN, rowstart, dinv, N);

        k_mm<128, false><<<mmGrid, 256, 0, stream>>>(X, W1, dinv, XW8, N);
        k_aggh<false, 0><<<2048, 256, 0, stream>>>(colN, rowstart, dinv, XW8,
                                                   bb1, H1, nullptr, nullptr, nullptr, N);
        k_aggh<false, 1><<<2048, 256, 0, stream>>>(colN, rowstart, dinv, XW8 + (size_t)N * 32,
                                                   bb1, H1, nullptr, nullptr, nullptr, N);
        k_mm<64, true><<<mmGrid, 256, 0, stream>>>(H1, W2, dinv, XW8, N);
        hipMemsetAsync(emb, 0, (size_t)(G * 64 + G) * 4, stream);   // emb,cnt adjacent
        k_aggh<true, 0><<<2048, 256, 0, stream>>>(colN, rowstart, dinv, XW8,
                                                  bb2, nullptr, bt, emb, cnt, N);
        k_aggh<true, 1><<<2048, 256, 0, stream>>>(colN, rowstart, dinv, XW8 + (size_t)N * 32,
                                                  bb2, nullptr, bt, emb, cnt, N);
    }
    k_head<<<G, 64, 0, stream>>>(emb1, cnt1, emb2, cnt2, fc1W, fc1b, fc2W, fc2b, out);
}

// Round 13
// 848.799 us; speedup vs baseline: 1.1300x; 1.1300x over previous
//
#include <hip/hip_runtime.h>
#include <hip/hip_fp16.h>
#include <cstdint>

// ---------------------------------------------------------------------------
// GCN Siamese. LDS-staged multisplit (dst>>8 buckets) -> per-bucket LDS
// counting sort -> node-major CSR -> fp8 gather aggregation.
// r13: 4-edges-per-instruction gathers. Evidence r7/r10/r12: agg time tracks
// gather-INSTRUCTION count (~20G instr/s ceiling), not bytes. Lane l = edge
// slot (l>>4) x feature chunk (l&15)*4; one dword gather = 4 fp8 feats; one
// wave instruction covers 4 edge rows. shfl_xor(16/32) merges edge slots.
// N=100000, E=3.2M, G=1024
// ---------------------------------------------------------------------------

#define NBSH 8                      // 256 nodes per bucket
#define CAPB 10240                  // per-bucket capacity (mean 8184, ~23 sigma)
#define SPLIT_T 512
#define SPLIT_EPT 28
#define SPLIT_CHUNK (SPLIT_T * SPLIT_EPT)   // 14336

__device__ __forceinline__ float fatomic(float* p, float v) {
    return unsafeAtomicAdd(p, v);   // hw global_atomic_add_f32
}
__device__ __forceinline__ float bf2f(unsigned short u) {
    union { unsigned int i; float f; } c; c.i = ((unsigned int)u) << 16; return c.f;
}
__device__ __forceinline__ unsigned short f2bf(float f) {
    union { float f; unsigned int i; } c; c.f = f;
    const unsigned int b = c.i;
    return (unsigned short)((b + 0x7FFF + ((b >> 16) & 1)) >> 16);   // RNE
}

#if defined(__has_builtin)
#if __has_builtin(__builtin_amdgcn_cvt_f32_fp8) && __has_builtin(__builtin_amdgcn_cvt_pk_fp8_f32)
#define HW_FP8 1
#endif
#endif

// fp8 e4m3 decode of byte k inside dword v (k compile-time constant)
__device__ __forceinline__ float fp8dec_sw(unsigned int b) {
    const unsigned int mag = (b & 0x7Fu) << 20;
    const float f = __uint_as_float(mag) * __uint_as_float(0x7B800000u);
    const unsigned int r = __float_as_uint(f) | ((b & 0x80u) << 24);
    return __uint_as_float(r);
}
#ifdef HW_FP8
#define FP8D(v, k) __builtin_amdgcn_cvt_f32_fp8((int)(v), (k))
#else
#define FP8D(v, k) fp8dec_sw(((v) >> ((k) * 8)) & 255u)
#endif

// f32 -> fp8 e4m3, RNE
__device__ __forceinline__ unsigned char fp8enc(float x) {
#ifdef HW_FP8
    const int v = __builtin_amdgcn_cvt_pk_fp8_f32(x, x, 0, false);
    return (unsigned char)(v & 0xFF);
#else
    const unsigned short h = __half_as_ushort(__float2half(x));
    const unsigned int s = (unsigned int)(h >> 15) << 7;
    const int e = (h >> 10) & 0x1F;
    const unsigned int m = h & 0x3FFu;
    if (e == 31) return (unsigned char)(s | 0x7E);
    if (e == 0) return (unsigned char)s;
    int E = e - 15 + 7;
    if (E >= 16) return (unsigned char)(s | 0x7E);
    if (E <= 0) {
        const unsigned int M = 0x400u | m;
        const int r = 16 - e;
        const unsigned int q = (M + (1u << (r - 1)) - 1u + ((M >> r) & 1u)) >> r;
        return (unsigned char)(s | (q > 7u ? 8u : q));
    }
    unsigned int q = (m + 63u + ((m >> 7) & 1u)) >> 7;
    if (q == 8u) { q = 0u; ++E; if (E >= 16) return (unsigned char)(s | 0x7E); }
    return (unsigned char)(s | ((unsigned int)E << 3) | q);
#endif
}

// ---- stage 1: multisplit into 391 buckets (dst>>8), dense run writes ------
__global__ __launch_bounds__(512) void k_split(const int* __restrict__ src,
                                               const int* __restrict__ dst,
                                               int* __restrict__ gcnt,
                                               int* __restrict__ colBkt,
                                               int E, int NBUK) {
    __shared__ int out[SPLIT_CHUNK];     // 57344 B
    __shared__ int bs[513];
    __shared__ int aux[512];
    const int t = threadIdx.x;
    const int e0 = blockIdx.x * SPLIT_CHUNK;

    int pk[SPLIT_EPT];
    int bk[SPLIT_EPT];

    aux[t] = 0;
    __syncthreads();

#pragma unroll
    for (int k = 0; k < SPLIT_EPT; ++k) {
        const int e = e0 + t + SPLIT_T * k;          // coalesced
        if (e < E) {
            const int d = dst[e];
            const int s = src[e];
            const int b = d >> NBSH;
            pk[k] = (s << NBSH) | (d & ((1 << NBSH) - 1));
            bk[k] = b;
            atomicAdd(&aux[b], 1);
        } else {
            bk[k] = -1;
        }
    }
    __syncthreads();

    for (int off = 1; off < 512; off <<= 1) {
        const int u = (t >= off) ? aux[t - off] : 0;
        __syncthreads();
        aux[t] += u;
        __syncthreads();
    }
    bs[t + 1] = aux[t];
    if (t == 0) bs[0] = 0;
    __syncthreads();

    aux[t] = 0;
    __syncthreads();

#pragma unroll
    for (int k = 0; k < SPLIT_EPT; ++k) {
        if (bk[k] >= 0) {
            const int pos = bs[bk[k]] + atomicAdd(&aux[bk[k]], 1);
            out[pos] = pk[k];
        }
    }
    __syncthreads();

    if (t < NBUK) {
        const int L = bs[t + 1] - bs[t];
        aux[t] = (L > 0) ? atomicAdd(&gcnt[t], L) : 0;   // goff
    } else if (t < 512) {
        aux[t] = 0;
    }
    __syncthreads();

    const int wid = t >> 6, lane = t & 63;
    for (int b = wid; b < NBUK; b += 8) {
        const int L = bs[b + 1] - bs[b];
        if (L == 0) continue;
        const int gp = aux[b];
        const size_t rb = (size_t)b * CAPB;
        for (int k = lane; k < L; k += 64) {
            const int p = gp + k;
            if (p < CAPB) colBkt[rb + p] = out[bs[b] + k];
        }
    }
}

// ---- stage 1b: scan bucket counts -> gbase ; rowstart[N] = total ----------
__global__ __launch_bounds__(512) void k_gscan(const int* __restrict__ gcnt,
                                               int* __restrict__ gbase,
                                               int* __restrict__ rowstart,
                                               int NBUK, int Nn) {
    __shared__ int sm[512];
    const int t = threadIdx.x;
    const int v = (t < NBUK) ? min(gcnt[t], CAPB) : 0;
    sm[t] = v;
    __syncthreads();
    for (int off = 1; off < 512; off <<= 1) {
        const int u = (t >= off) ? sm[t - off] : 0;
        __syncthreads();
        sm[t] += u;
        __syncthreads();
    }
    if (t < NBUK) gbase[t] = sm[t] - v;  // exclusive
    if (t == 511) rowstart[Nn] = sm[511];
}

// ---- stage 2: per-bucket LDS counting sort -> colN, rowstart, dinv --------
__global__ __launch_bounds__(256) void k_bsort(const int* __restrict__ colBkt,
                                               const int* __restrict__ gcnt,
                                               const int* __restrict__ gbase,
                                               int* __restrict__ colN,
                                               int* __restrict__ rowstart,
                                               float* __restrict__ dinv,
                                               int Nn) {
    __shared__ int in[CAPB];             // 40960 B
    __shared__ int lb[257];
    __shared__ int fill[256];
    const int b = blockIdx.x;
    const int t = threadIdx.x;
    const int L = min(gcnt[b], CAPB);
    const size_t rb = (size_t)b * CAPB;
    for (int k = t; k < L; k += 256) in[k] = colBkt[rb + k];
    fill[t] = 0;
    __syncthreads();
    for (int k = t; k < L; k += 256) atomicAdd(&fill[in[k] & 255], 1);
    __syncthreads();
    for (int off = 1; off < 256; off <<= 1) {
        const int u = (t >= off) ? fill[t - off] : 0;
        __syncthreads();
        fill[t] += u;
        __syncthreads();
    }
    lb[t + 1] = fill[t];
    if (t == 0) lb[0] = 0;
    __syncthreads();
    const int bb = gbase[b];
    const int node = (b << NBSH) + t;
    if (node < Nn) {
        rowstart[node] = bb + lb[t];
        dinv[node] = rsqrtf((float)(lb[t + 1] - lb[t]) + 1.0f);
    }
    fill[t] = 0;
    __syncthreads();
    for (int k = t; k < L; k += 256) {
        const int v = in[k];
        const int n = v & 255;
        const int pos = bb + lb[n] + atomicAdd(&fill[n], 1);
        colN[pos] = v >> NBSH;
    }
}

// Y[row][64] = fp8(dinv[row] * (X@W)[row]) ; X is f32 or bf16
template <int K, bool BF16IN>
__global__ __launch_bounds__(256, 4) void k_mm(const void* __restrict__ Xv,
                                               const float* __restrict__ W,
                                               const float* __restrict__ dinv,
                                               unsigned char* __restrict__ Y, int n) {
    __shared__ float WL[K * 64];
    __shared__ float XT[32 * K];
    const int tid = threadIdx.x;
    for (int i = tid * 4; i < K * 64; i += 1024)
        *(float4*)&WL[i] = *(const float4*)&W[i];
    const int rowBase = blockIdx.x * 32;
    const int rows = min(32, n - rowBase);
    if (BF16IN) {
        const unsigned short* xs = (const unsigned short*)Xv + (size_t)rowBase * K;
        for (int i = tid * 4; i < rows * K; i += 1024) {
            const ushort4 u = *(const ushort4*)&xs[i];
            XT[i + 0] = bf2f(u.x); XT[i + 1] = bf2f(u.y);
            XT[i + 2] = bf2f(u.z); XT[i + 3] = bf2f(u.w);
        }
    } else {
        const float* xs = (const float*)Xv + (size_t)rowBase * K;
        for (int i = tid * 4; i < rows * K; i += 1024)
            *(float4*)&XT[i] = *(const float4*)&xs[i];
    }
    __syncthreads();
    const int colf = tid & 63;
    const int rg = tid >> 6;
    float acc[8] = {};
#pragma unroll 4
    for (int k4 = 0; k4 < K / 4; ++k4) {
        const float w0 = WL[(k4 * 4 + 0) * 64 + colf];
        const float w1 = WL[(k4 * 4 + 1) * 64 + colf];
        const float w2 = WL[(k4 * 4 + 2) * 64 + colf];
        const float w3 = WL[(k4 * 4 + 3) * 64 + colf];
#pragma unroll
        for (int r = 0; r < 8; ++r) {
            const float4 xv = *(const float4*)&XT[(rg * 8 + r) * K + k4 * 4];
            acc[r] += xv.x * w0 + xv.y * w1 + xv.z * w2 + xv.w * w3;
        }
    }
#pragma unroll
    for (int r = 0; r < 8; ++r) {
        const int row = rowBase + rg * 8 + r;
        if (row < n)
            __builtin_nontemporal_store(fp8enc(dinv[row] * acc[r]),
                                        &Y[(size_t)row * 64 + colf]);
    }
}

// node-major CSR aggregation, 4 edges per gather instruction:
// lane l -> edge slot jj=l>>4, feature chunk c16=l&15 (features c16*4..+4).
// One dword gather = 4 fp8 features of one row; wave instr = 4 rows.
// shfl_xor(16,32) merges edge slots; epilogue on lanes 0..15.
template <bool POOL>
__global__ __launch_bounds__(256) void k_agg(const int* __restrict__ colN,
                                             const int* __restrict__ rowstart,
                                             const float* __restrict__ dinv,
                                             const unsigned char* __restrict__ XW8,
                                             const float* __restrict__ bias,
                                             unsigned short* __restrict__ Hout,
                                             const int* __restrict__ batch,
                                             float* __restrict__ emb,
                                             float* __restrict__ cnt, int Nn) {
    const int lane = threadIdx.x & 63;
    const int c16 = lane & 15;           // feature chunk
    const int jj = lane >> 4;            // edge slot 0..3
    const int boff = c16 * 4;
    const int wid = (blockIdx.x * blockDim.x + threadIdx.x) >> 6;
    const int nw = (gridDim.x * blockDim.x) >> 6;
    const float bl0 = bias[boff + 0], bl1 = bias[boff + 1];
    const float bl2 = bias[boff + 2], bl3 = bias[boff + 3];
    for (int i = wid; i < Nn; i += nw) {
        const int s = rowstart[i], e = rowstart[i + 1];
        float a0 = 0.f, a1 = 0.f, a2 = 0.f, a3 = 0.f;
        int j = s;
        for (; j + 16 <= e; j += 16) {   // 4 gather instrs in flight = 16 edges
            const int cA = colN[j + jj];
            const int cB = colN[j + 4 + jj];
            const int cC = colN[j + 8 + jj];
            const int cD = colN[j + 12 + jj];
            const unsigned int vA = *(const unsigned int*)&XW8[(size_t)cA * 64 + boff];
            const unsigned int vB = *(const unsigned int*)&XW8[(size_t)cB * 64 + boff];
            const unsigned int vC = *(const unsigned int*)&XW8[(size_t)cC * 64 + boff];
            const unsigned int vD = *(const unsigned int*)&XW8[(size_t)cD * 64 + boff];
            a0 += (FP8D(vA, 0) + FP8D(vB, 0)) + (FP8D(vC, 0) + FP8D(vD, 0));
            a1 += (FP8D(vA, 1) + FP8D(vB, 1)) + (FP8D(vC, 1) + FP8D(vD, 1));
            a2 += (FP8D(vA, 2) + FP8D(vB, 2)) + (FP8D(vC, 2) + FP8D(vD, 2));
            a3 += (FP8D(vA, 3) + FP8D(vB, 3)) + (FP8D(vC, 3) + FP8D(vD, 3));
        }
        for (; j < e; j += 4) {          // masked tail, 4 edges per step
            if (j + jj < e) {
                const int cA = colN[j + jj];
                const unsigned int vA = *(const unsigned int*)&XW8[(size_t)cA * 64 + boff];
                a0 += FP8D(vA, 0);
                a1 += FP8D(vA, 1);
                a2 += FP8D(vA, 2);
                a3 += FP8D(vA, 3);
            }
        }
        a0 += __shfl_xor(a0, 16); a0 += __shfl_xor(a0, 32);
        a1 += __shfl_xor(a1, 16); a1 += __shfl_xor(a1, 32);
        a2 += __shfl_xor(a2, 16); a2 += __shfl_xor(a2, 32);
        a3 += __shfl_xor(a3, 16); a3 += __shfl_xor(a3, 32);
        if (jj == 0) {
            const float di = dinv[i];
            const unsigned int sv = *(const unsigned int*)&XW8[(size_t)i * 64 + boff];
            const float v0 = fmaxf(di * (a0 + FP8D(sv, 0)) + bl0, 0.0f);
            const float v1 = fmaxf(di * (a1 + FP8D(sv, 1)) + bl1, 0.0f);
            const float v2 = fmaxf(di * (a2 + FP8D(sv, 2)) + bl2, 0.0f);
            const float v3 = fmaxf(di * (a3 + FP8D(sv, 3)) + bl3, 0.0f);
            if (POOL) {
                const int g = batch[i];
                float* ep = &emb[(size_t)g * 64 + boff];
                fatomic(ep + 0, v0); fatomic(ep + 1, v1);
                fatomic(ep + 2, v2); fatomic(ep + 3, v3);
                if (c16 == 0) fatomic(&cnt[g], 1.0f);
            } else {
                ushort4 o;
                o.x = f2bf(v0); o.y = f2bf(v1); o.z = f2bf(v2); o.w = f2bf(v3);
                *(ushort4*)&Hout[(size_t)i * 64 + boff] = o;
            }
        }
    }
}

// head: emb -> [e1,e2,|e1-e2|] @ fc1 -> relu -> @ fc2 -> sigmoid
__global__ __launch_bounds__(64) void k_head(const float* __restrict__ emb1, const float* __restrict__ cnt1,
                                             const float* __restrict__ emb2, const float* __restrict__ cnt2,
                                             const float* __restrict__ fc1W, const float* __restrict__ fc1b,
                                             const float* __restrict__ fc2W, const float* __restrict__ fc2b,
                                             float* __restrict__ out) {
    const int g = blockIdx.x;
    const int lane = threadIdx.x;
    __shared__ float comb[192];
    const float c1 = fmaxf(cnt1[g], 1.0f), c2 = fmaxf(cnt2[g], 1.0f);
    const float e1 = emb1[g * 64 + lane] / c1;
    const float e2 = emb2[g * 64 + lane] / c2;
    comb[lane] = e1;
    comb[64 + lane] = e2;
    comb[128 + lane] = fabsf(e1 - e2);
    __syncthreads();
    float acc = fc1b[lane];
    for (int k = 0; k < 192; ++k) acc += comb[k] * fc1W[k * 64 + lane];
    const float o1 = fmaxf(acc, 0.0f);
    float p = o1 * fc2W[lane];
#pragma unroll
    for (int off = 32; off > 0; off >>= 1) p += __shfl_xor(p, off);
    if (lane == 0) out[g] = 1.0f / (1.0f + expf(-(p + fc2b[0])));
}

extern "C" void kernel_launch(void* const* d_in, const int* in_sizes, int n_in,
                              void* d_out, int out_size, void* d_ws, size_t ws_size,
                              hipStream_t stream) {
    const float* x1   = (const float*)d_in[0];
    const int*   ei1  = (const int*)d_in[1];
    const int*   bt1  = (const int*)d_in[2];
    const float* x2   = (const float*)d_in[3];
    const int*   ei2  = (const int*)d_in[4];
    const int*   bt2  = (const int*)d_in[5];
    const float* W1   = (const float*)d_in[6];
    const float* bb1  = (const float*)d_in[7];
    const float* W2   = (const float*)d_in[8];
    const float* bb2  = (const float*)d_in[9];
    const float* fc1W = (const float*)d_in[10];
    const float* fc1b = (const float*)d_in[11];
    const float* fc2W = (const float*)d_in[12];
    const float* fc2b = (const float*)d_in[13];
    float* out = (float*)d_out;

    const int N = in_sizes[0] / 128;
    const int E = in_sizes[1] / 2;
    const int G = out_size;
    const int NBUK = (N + 255) >> NBSH;              // 391
    const int nchunks = (E + SPLIT_CHUNK - 1) / SPLIT_CHUNK;

    // 16B-aligned workspace carve-out
    char* base = (char*)d_ws;
    size_t off = 0;
    auto carve = [&](size_t bytes) {
        void* p = base + off;
        off = (off + bytes + 15) & ~(size_t)15;
        return p;
    };
    float* dinv   = (float*)carve((size_t)N * 4);
    float* emb1   = (float*)carve((size_t)G * 64 * 4);
    float* cnt1   = (float*)carve((size_t)G * 4);
    float* emb2   = (float*)carve((size_t)G * 64 * 4);
    float* cnt2   = (float*)carve((size_t)G * 4);
    int* rowstart = (int*)carve((size_t)(N + 1) * 4);
    int* gcnt     = (int*)carve(512 * 4);
    int* gbase    = (int*)carve(512 * 4);
    int* colBkt   = (int*)carve((size_t)NBUK * CAPB * 4);   // 16.0 MB
    int* colN     = (int*)carve((size_t)E * 4);             // 12.8 MB
    unsigned char* XW8 = (unsigned char*)carve((size_t)N * 64);
    unsigned short* H1 = (unsigned short*)colBkt;   // overlay (dead after bsort)

    const int mmGrid = (N + 31) / 32;

    for (int br = 0; br < 2; ++br) {
        const float* X = br ? x2 : x1;
        const int* ei  = br ? ei2 : ei1;
        const int* bt  = br ? bt2 : bt1;
        float* emb = br ? emb2 : emb1;
        float* cnt = br ? cnt2 : cnt1;
        const int* srcp = ei;
        const int* dstp = ei + E;

        hipMemsetAsync(gcnt, 0, 512 * 4, stream);
        k_split<<<nchunks, SPLIT_T, 0, stream>>>(srcp, dstp, gcnt, colBkt, E, NBUK);
        k_gscan<<<1, 512, 0, stream>>>(gcnt, gbase, rowstart, NBUK, N);
        k_bsort<<<NBUK, 256, 0, stream>>>(colBkt, gcnt, gbase, colN, rowstart, dinv, N);

        k_mm<128, false><<<mmGrid, 256, 0, stream>>>(X, W1, dinv, XW8, N);
        k_agg<false><<<2048, 256, 0, stream>>>(colN, rowstart, dinv, XW8, bb1,
                                               H1, nullptr, nullptr, nullptr, N);
        k_mm<64, true><<<mmGrid, 256, 0, stream>>>(H1, W2, dinv, XW8, N);
        hipMemsetAsync(emb, 0, (size_t)(G * 64 + G) * 4, stream);   // emb,cnt adjacent
        k_agg<true><<<2048, 256, 0, stream>>>(colN, rowstart, dinv, XW8, bb2,
                                              nullptr, bt, emb, cnt, N);
    }
    k_head<<<G, 64, 0, stream>>>(emb1, cnt1, emb2, cnt2, fc1W, fc1b, fc2W, fc2b, out);
}

// Round 14
// 781.192 us; speedup vs baseline: 1.2278x; 1.0865x over previous
//
#include <hip/hip_runtime.h>
#include <hip/hip_fp16.h>
#include <cstdint>

// ---------------------------------------------------------------------------
// GCN Siamese. LDS-staged multisplit (dst>>8 buckets) -> per-bucket LDS
// counting sort -> node-major CSR -> unroll-16 fp8 byte-gather aggregation.
// r14 = r10's k_agg (measured at the ~21G line-request/s gather floor) +
//       r13's occupancy-fixed k_mm. No NT hints on agg streams (r11 lesson).
// N=100000, E=3.2M, G=1024
// ---------------------------------------------------------------------------

#define NBSH 8                      // 256 nodes per bucket
#define CAPB 10240                  // per-bucket capacity (mean 8184, ~23 sigma)
#define SPLIT_T 512
#define SPLIT_EPT 28
#define SPLIT_CHUNK (SPLIT_T * SPLIT_EPT)   // 14336

__device__ __forceinline__ float fatomic(float* p, float v) {
    return unsafeAtomicAdd(p, v);   // hw global_atomic_add_f32
}
__device__ __forceinline__ float bf2f(unsigned short u) {
    union { unsigned int i; float f; } c; c.i = ((unsigned int)u) << 16; return c.f;
}
__device__ __forceinline__ unsigned short f2bf(float f) {
    union { float f; unsigned int i; } c; c.f = f;
    const unsigned int b = c.i;
    return (unsigned short)((b + 0x7FFF + ((b >> 16) & 1)) >> 16);   // RNE
}

#if defined(__has_builtin)
#if __has_builtin(__builtin_amdgcn_cvt_f32_fp8) && __has_builtin(__builtin_amdgcn_cvt_pk_fp8_f32)
#define HW_FP8 1
#endif
#endif

// fp8 e4m3 decode (byte value in bits 0..7)
__device__ __forceinline__ float fp8dec(unsigned int b) {
#ifdef HW_FP8
    return __builtin_amdgcn_cvt_f32_fp8((int)b, 0);
#else
    const unsigned int mag = (b & 0x7Fu) << 20;
    const float f = __uint_as_float(mag) * __uint_as_float(0x7B800000u);
    const unsigned int r = __float_as_uint(f) | ((b & 0x80u) << 24);
    return __uint_as_float(r);
#endif
}

// f32 -> fp8 e4m3, RNE
__device__ __forceinline__ unsigned char fp8enc(float x) {
#ifdef HW_FP8
    const int v = __builtin_amdgcn_cvt_pk_fp8_f32(x, x, 0, false);
    return (unsigned char)(v & 0xFF);
#else
    const unsigned short h = __half_as_ushort(__float2half(x));
    const unsigned int s = (unsigned int)(h >> 15) << 7;
    const int e = (h >> 10) & 0x1F;
    const unsigned int m = h & 0x3FFu;
    if (e == 31) return (unsigned char)(s | 0x7E);
    if (e == 0) return (unsigned char)s;
    int E = e - 15 + 7;
    if (E >= 16) return (unsigned char)(s | 0x7E);
    if (E <= 0) {
        const unsigned int M = 0x400u | m;
        const int r = 16 - e;
        const unsigned int q = (M + (1u << (r - 1)) - 1u + ((M >> r) & 1u)) >> r;
        return (unsigned char)(s | (q > 7u ? 8u : q));
    }
    unsigned int q = (m + 63u + ((m >> 7) & 1u)) >> 7;
    if (q == 8u) { q = 0u; ++E; if (E >= 16) return (unsigned char)(s | 0x7E); }
    return (unsigned char)(s | ((unsigned int)E << 3) | q);
#endif
}

// ---- stage 1: multisplit into 391 buckets (dst>>8), dense run writes ------
__global__ __launch_bounds__(512) void k_split(const int* __restrict__ src,
                                               const int* __restrict__ dst,
                                               int* __restrict__ gcnt,
                                               int* __restrict__ colBkt,
                                               int E, int NBUK) {
    __shared__ int out[SPLIT_CHUNK];     // 57344 B
    __shared__ int bs[513];
    __shared__ int aux[512];
    const int t = threadIdx.x;
    const int e0 = blockIdx.x * SPLIT_CHUNK;

    int pk[SPLIT_EPT];
    int bk[SPLIT_EPT];

    aux[t] = 0;
    __syncthreads();

#pragma unroll
    for (int k = 0; k < SPLIT_EPT; ++k) {
        const int e = e0 + t + SPLIT_T * k;          // coalesced
        if (e < E) {
            const int d = dst[e];
            const int s = src[e];
            const int b = d >> NBSH;
            pk[k] = (s << NBSH) | (d & ((1 << NBSH) - 1));
            bk[k] = b;
            atomicAdd(&aux[b], 1);
        } else {
            bk[k] = -1;
        }
    }
    __syncthreads();

    for (int off = 1; off < 512; off <<= 1) {
        const int u = (t >= off) ? aux[t - off] : 0;
        __syncthreads();
        aux[t] += u;
        __syncthreads();
    }
    bs[t + 1] = aux[t];
    if (t == 0) bs[0] = 0;
    __syncthreads();

    aux[t] = 0;
    __syncthreads();

#pragma unroll
    for (int k = 0; k < SPLIT_EPT; ++k) {
        if (bk[k] >= 0) {
            const int pos = bs[bk[k]] + atomicAdd(&aux[bk[k]], 1);
            out[pos] = pk[k];
        }
    }
    __syncthreads();

    if (t < NBUK) {
        const int L = bs[t + 1] - bs[t];
        aux[t] = (L > 0) ? atomicAdd(&gcnt[t], L) : 0;   // goff
    } else if (t < 512) {
        aux[t] = 0;
    }
    __syncthreads();

    const int wid = t >> 6, lane = t & 63;
    for (int b = wid; b < NBUK; b += 8) {
        const int L = bs[b + 1] - bs[b];
        if (L == 0) continue;
        const int gp = aux[b];
        const size_t rb = (size_t)b * CAPB;
        for (int k = lane; k < L; k += 64) {
            const int p = gp + k;
            if (p < CAPB) colBkt[rb + p] = out[bs[b] + k];
        }
    }
}

// ---- stage 1b: scan bucket counts -> gbase ; rowstart[N] = total ----------
__global__ __launch_bounds__(512) void k_gscan(const int* __restrict__ gcnt,
                                               int* __restrict__ gbase,
                                               int* __restrict__ rowstart,
                                               int NBUK, int Nn) {
    __shared__ int sm[512];
    const int t = threadIdx.x;
    const int v = (t < NBUK) ? min(gcnt[t], CAPB) : 0;
    sm[t] = v;
    __syncthreads();
    for (int off = 1; off < 512; off <<= 1) {
        const int u = (t >= off) ? sm[t - off] : 0;
        __syncthreads();
        sm[t] += u;
        __syncthreads();
    }
    if (t < NBUK) gbase[t] = sm[t] - v;  // exclusive
    if (t == 511) rowstart[Nn] = sm[511];
}

// ---- stage 2: per-bucket LDS counting sort -> colN, rowstart, dinv --------
__global__ __launch_bounds__(256) void k_bsort(const int* __restrict__ colBkt,
                                               const int* __restrict__ gcnt,
                                               const int* __restrict__ gbase,
                                               int* __restrict__ colN,
                                               int* __restrict__ rowstart,
                                               float* __restrict__ dinv,
                                               int Nn) {
    __shared__ int in[CAPB];             // 40960 B
    __shared__ int lb[257];
    __shared__ int fill[256];
    const int b = blockIdx.x;
    const int t = threadIdx.x;
    const int L = min(gcnt[b], CAPB);
    const size_t rb = (size_t)b * CAPB;
    for (int k = t; k < L; k += 256) in[k] = colBkt[rb + k];
    fill[t] = 0;
    __syncthreads();
    for (int k = t; k < L; k += 256) atomicAdd(&fill[in[k] & 255], 1);
    __syncthreads();
    for (int off = 1; off < 256; off <<= 1) {
        const int u = (t >= off) ? fill[t - off] : 0;
        __syncthreads();
        fill[t] += u;
        __syncthreads();
    }
    lb[t + 1] = fill[t];
    if (t == 0) lb[0] = 0;
    __syncthreads();
    const int bb = gbase[b];
    const int node = (b << NBSH) + t;
    if (node < Nn) {
        rowstart[node] = bb + lb[t];
        dinv[node] = rsqrtf((float)(lb[t + 1] - lb[t]) + 1.0f);
    }
    fill[t] = 0;
    __syncthreads();
    for (int k = t; k < L; k += 256) {
        const int v = in[k];
        const int n = v & 255;
        const int pos = bb + lb[n] + atomicAdd(&fill[n], 1);
        colN[pos] = v >> NBSH;
    }
}

// Y[row][64] = fp8(dinv[row] * (X@W)[row]) ; X is f32 or bf16
// launch_bounds(256,4): caps VGPR (r10's unbounded build hit 256 VGPR/0.5% occ)
template <int K, bool BF16IN>
__global__ __launch_bounds__(256, 4) void k_mm(const void* __restrict__ Xv,
                                               const float* __restrict__ W,
                                               const float* __restrict__ dinv,
                                               unsigned char* __restrict__ Y, int n) {
    __shared__ float WL[K * 64];
    __shared__ float XT[32 * K];
    const int tid = threadIdx.x;
    for (int i = tid * 4; i < K * 64; i += 1024)
        *(float4*)&WL[i] = *(const float4*)&W[i];
    const int rowBase = blockIdx.x * 32;
    const int rows = min(32, n - rowBase);
    if (BF16IN) {
        const unsigned short* xs = (const unsigned short*)Xv + (size_t)rowBase * K;
        for (int i = tid * 4; i < rows * K; i += 1024) {
            const ushort4 u = *(const ushort4*)&xs[i];
            XT[i + 0] = bf2f(u.x); XT[i + 1] = bf2f(u.y);
            XT[i + 2] = bf2f(u.z); XT[i + 3] = bf2f(u.w);
        }
    } else {
        const float* xs = (const float*)Xv + (size_t)rowBase * K;
        for (int i = tid * 4; i < rows * K; i += 1024)
            *(float4*)&XT[i] = *(const float4*)&xs[i];
    }
    __syncthreads();
    const int colf = tid & 63;
    const int rg = tid >> 6;
    float acc[8] = {};
#pragma unroll 4
    for (int k4 = 0; k4 < K / 4; ++k4) {
        const float w0 = WL[(k4 * 4 + 0) * 64 + colf];
        const float w1 = WL[(k4 * 4 + 1) * 64 + colf];
        const float w2 = WL[(k4 * 4 + 2) * 64 + colf];
        const float w3 = WL[(k4 * 4 + 3) * 64 + colf];
#pragma unroll
        for (int r = 0; r < 8; ++r) {
            const float4 xv = *(const float4*)&XT[(rg * 8 + r) * K + k4 * 4];
            acc[r] += xv.x * w0 + xv.y * w1 + xv.z * w2 + xv.w * w3;
        }
    }
#pragma unroll
    for (int r = 0; r < 8; ++r) {
        const int row = rowBase + rg * 8 + r;
        if (row < n) Y[(size_t)row * 64 + colf] = fp8enc(dinv[row] * acc[r]);
    }
}

// node-major CSR aggregation (r10 form): wave per node, lane = feature,
// unroll-16 fp8 byte gathers. Wave-uniform idx loads ride the scalar/L1-hit
// path; the 16 row-gathers are the 3.2M line-requests/pass at the HW floor.
template <bool POOL>
__global__ __launch_bounds__(256) void k_agg(const int* __restrict__ colN,
                                             const int* __restrict__ rowstart,
                                             const float* __restrict__ dinv,
                                             const unsigned char* __restrict__ XW8,
                                             const float* __restrict__ bias,
                                             unsigned short* __restrict__ Hout,
                                             const int* __restrict__ batch,
                                             float* __restrict__ emb,
                                             float* __restrict__ cnt, int Nn) {
    const int lane = threadIdx.x & 63;
    const int wid = (blockIdx.x * blockDim.x + threadIdx.x) >> 6;
    const int nw = (gridDim.x * blockDim.x) >> 6;
    const float bl = bias[lane];
    for (int i = wid; i < Nn; i += nw) {
        const int s = rowstart[i], e = rowstart[i + 1];
        float acc = 0.0f;
        int j = s;
        for (; j + 16 <= e; j += 16) {
            int c[16];
#pragma unroll
            for (int q = 0; q < 16; ++q) c[q] = colN[j + q];
            unsigned int b[16];
#pragma unroll
            for (int q = 0; q < 16; ++q) b[q] = XW8[(size_t)c[q] * 64 + lane];
            float t0 = 0.f, t1 = 0.f;
#pragma unroll
            for (int q = 0; q < 8; ++q) t0 += fp8dec(b[q]);
#pragma unroll
            for (int q = 8; q < 16; ++q) t1 += fp8dec(b[q]);
            acc += t0 + t1;
        }
        for (; j + 4 <= e; j += 4) {
            const float a0 = fp8dec(XW8[(size_t)colN[j + 0] * 64 + lane]);
            const float a1 = fp8dec(XW8[(size_t)colN[j + 1] * 64 + lane]);
            const float a2 = fp8dec(XW8[(size_t)colN[j + 2] * 64 + lane]);
            const float a3 = fp8dec(XW8[(size_t)colN[j + 3] * 64 + lane]);
            acc += (a0 + a1) + (a2 + a3);
        }
        for (; j < e; ++j)
            acc += fp8dec(XW8[(size_t)colN[j] * 64 + lane]);
        const float di = dinv[i];
        const float self = fp8dec(XW8[(size_t)i * 64 + lane]);
        const float v = fmaxf(di * (acc + self) + bl, 0.0f);
        if (POOL) {
            const int g = batch[i];
            fatomic(&emb[(size_t)g * 64 + lane], v);
            if (lane == 0) fatomic(&cnt[g], 1.0f);
        } else {
            Hout[(size_t)i * 64 + lane] = f2bf(v);
        }
    }
}

// head: emb -> [e1,e2,|e1-e2|] @ fc1 -> relu -> @ fc2 -> sigmoid
__global__ __launch_bounds__(64) void k_head(const float* __restrict__ emb1, const float* __restrict__ cnt1,
                                             const float* __restrict__ emb2, const float* __restrict__ cnt2,
                                             const float* __restrict__ fc1W, const float* __restrict__ fc1b,
                                             const float* __restrict__ fc2W, const float* __restrict__ fc2b,
                                             float* __restrict__ out) {
    const int g = blockIdx.x;
    const int lane = threadIdx.x;
    __shared__ float comb[192];
    const float c1 = fmaxf(cnt1[g], 1.0f), c2 = fmaxf(cnt2[g], 1.0f);
    const float e1 = emb1[g * 64 + lane] / c1;
    const float e2 = emb2[g * 64 + lane] / c2;
    comb[lane] = e1;
    comb[64 + lane] = e2;
    comb[128 + lane] = fabsf(e1 - e2);
    __syncthreads();
    float acc = fc1b[lane];
    for (int k = 0; k < 192; ++k) acc += comb[k] * fc1W[k * 64 + lane];
    const float o1 = fmaxf(acc, 0.0f);
    float p = o1 * fc2W[lane];
#pragma unroll
    for (int off = 32; off > 0; off >>= 1) p += __shfl_xor(p, off);
    if (lane == 0) out[g] = 1.0f / (1.0f + expf(-(p + fc2b[0])));
}

extern "C" void kernel_launch(void* const* d_in, const int* in_sizes, int n_in,
                              void* d_out, int out_size, void* d_ws, size_t ws_size,
                              hipStream_t stream) {
    const float* x1   = (const float*)d_in[0];
    const int*   ei1  = (const int*)d_in[1];
    const int*   bt1  = (const int*)d_in[2];
    const float* x2   = (const float*)d_in[3];
    const int*   ei2  = (const int*)d_in[4];
    const int*   bt2  = (const int*)d_in[5];
    const float* W1   = (const float*)d_in[6];
    const float* bb1  = (const float*)d_in[7];
    const float* W2   = (const float*)d_in[8];
    const float* bb2  = (const float*)d_in[9];
    const float* fc1W = (const float*)d_in[10];
    const float* fc1b = (const float*)d_in[11];
    const float* fc2W = (const float*)d_in[12];
    const float* fc2b = (const float*)d_in[13];
    float* out = (float*)d_out;

    const int N = in_sizes[0] / 128;
    const int E = in_sizes[1] / 2;
    const int G = out_size;
    const int NBUK = (N + 255) >> NBSH;              // 391
    const int nchunks = (E + SPLIT_CHUNK - 1) / SPLIT_CHUNK;

    // 16B-aligned workspace carve-out
    char* base = (char*)d_ws;
    size_t off = 0;
    auto carve = [&](size_t bytes) {
        void* p = base + off;
        off = (off + bytes + 15) & ~(size_t)15;
        return p;
    };
    float* dinv   = (float*)carve((size_t)N * 4);
    float* emb1   = (float*)carve((size_t)G * 64 * 4);
    float* cnt1   = (float*)carve((size_t)G * 4);
    float* emb2   = (float*)carve((size_t)G * 64 * 4);
    float* cnt2   = (float*)carve((size_t)G * 4);
    int* rowstart = (int*)carve((size_t)(N + 1) * 4);
    int* gcnt     = (int*)carve(512 * 4);
    int* gbase    = (int*)carve(512 * 4);
    int* colBkt   = (int*)carve((size_t)NBUK * CAPB * 4);   // 16.0 MB
    int* colN     = (int*)carve((size_t)E * 4);             // 12.8 MB
    unsigned char* XW8 = (unsigned char*)carve((size_t)N * 64);
    unsigned short* H1 = (unsigned short*)colBkt;   // overlay (dead after bsort)

    const int mmGrid = (N + 31) / 32;

    for (int br = 0; br < 2; ++br) {
        const float* X = br ? x2 : x1;
        const int* ei  = br ? ei2 : ei1;
        const int* bt  = br ? bt2 : bt1;
        float* emb = br ? emb2 : emb1;
        float* cnt = br ? cnt2 : cnt1;
        const int* srcp = ei;
        const int* dstp = ei + E;

        hipMemsetAsync(gcnt, 0, 512 * 4, stream);
        k_split<<<nchunks, SPLIT_T, 0, stream>>>(srcp, dstp, gcnt, colBkt, E, NBUK);
        k_gscan<<<1, 512, 0, stream>>>(gcnt, gbase, rowstart, NBUK, N);
        k_bsort<<<NBUK, 256, 0, stream>>>(colBkt, gcnt, gbase, colN, rowstart, dinv, N);

        k_mm<128, false><<<mmGrid, 256, 0, stream>>>(X, W1, dinv, XW8, N);
        k_agg<false><<<2048, 256, 0, stream>>>(colN, rowstart, dinv, XW8, bb1,
                                               H1, nullptr, nullptr, nullptr, N);
        k_mm<64, true><<<mmGrid, 256, 0, stream>>>(H1, W2, dinv, XW8, N);
        hipMemsetAsync(emb, 0, (size_t)(G * 64 + G) * 4, stream);   // emb,cnt adjacent
        k_agg<true><<<2048, 256, 0, stream>>>(colN, rowstart, dinv, XW8, bb2,
                                              nullptr, bt, emb, cnt, N);
    }
    k_head<<<G, 64, 0, stream>>>(emb1, cnt1, emb2, cnt2, fc1W, fc1b, fc2W, fc2b, out);
}